// Round 1
// baseline (306.841 us; speedup 1.0000x reference)
//
#include <hip/hip_runtime.h>

// Problem: B=16, C=64, H=W=192, K=3 (fixed by setup_inputs).
// out[b,c,h,w] = sum_{i,j in 0..2} ker[b,c,i,j] * x0[b,c,h+i-1,w+j-1]  (zero pad)
// ker[b,c,i,j] = sum_k hid[b,k] * w2[(c*9 + i*3 + j), k]
// hid[b,k]     = leaky_relu(sum_m d[b,m] * w1[k,m], 0.1)

#define BB 16
#define CC 64
#define HH 192
#define WW 192
#define KK2 9          // 3x3
#define KERLEN (CC * KK2)   // 576 per batch

// ---- Kernel 1: generate the 1024 per-(b,c) 3x3 kernels into d_ws ----
__global__ __launch_bounds__(256) void gen_kernels(
    const float* __restrict__ d,   // (B, C)
    const float* __restrict__ w1,  // (C, C) row-major: w1[j, m]
    const float* __restrict__ w2,  // (C*9, C) row-major: w2[o, k]
    float* __restrict__ ker)       // (B*C*9)
{
    __shared__ float dd[CC];
    __shared__ float hid[CC];
    const int b = blockIdx.x;
    const int t = threadIdx.x;

    if (t < CC) dd[t] = d[b * CC + t];
    __syncthreads();

    if (t < CC) {
        const float* w1r = w1 + t * CC;   // hid[b,t] = dot(d[b,:], w1[t,:])
        float acc = 0.f;
        #pragma unroll 8
        for (int m = 0; m < CC; ++m) acc += dd[m] * w1r[m];
        hid[t] = acc > 0.f ? acc : 0.1f * acc;
    }
    __syncthreads();

    for (int o = t; o < KERLEN; o += 256) {
        const float* w2r = w2 + o * CC;   // ker[b, o] = dot(hid[b,:], w2[o,:])
        float acc = 0.f;
        #pragma unroll 8
        for (int k = 0; k < CC; ++k) acc += hid[k] * w2r[k];
        ker[b * KERLEN + o] = acc;
    }
}

// ---- Kernel 2: depthwise 3x3 conv, one block per (b,c) plane ----
__global__ __launch_bounds__(256) void dconv3x3(
    const float* __restrict__ x,    // (B*C, H, W)
    const float* __restrict__ ker,  // (B*C, 9)
    float* __restrict__ out)        // (B*C, H, W)
{
    const int QW = WW / 4;          // 48 float4s per row
    const int bc = blockIdx.x;
    const float* __restrict__ xp = x + (size_t)bc * HH * WW;
    float* __restrict__ op = out + (size_t)bc * HH * WW;

    // Block-uniform kernel coefficients (compiler scalarizes these loads).
    const float* kp = ker + bc * KK2;
    float kk[9];
    #pragma unroll
    for (int i = 0; i < 9; ++i) kk[i] = kp[i];

    for (int idx = threadIdx.x; idx < HH * QW; idx += 256) {
        const int h = idx / QW;
        const int qw = idx - h * QW;
        const int w = qw * 4;

        float a0 = 0.f, a1 = 0.f, a2 = 0.f, a3 = 0.f;
        #pragma unroll
        for (int dh = -1; dh <= 1; ++dh) {
            const int r = h + dh;
            if (r < 0 || r >= HH) continue;
            const float* row = xp + r * WW + w;
            const float4 c = *(const float4*)row;
            const float v0 = (w > 0) ? row[-1] : 0.f;      // col w-1
            const float v5 = (w + 4 < WW) ? row[4] : 0.f;  // col w+4
            const float v1 = c.x, v2 = c.y, v3 = c.z, v4 = c.w;
            const float k0 = kk[(dh + 1) * 3 + 0];
            const float k1 = kk[(dh + 1) * 3 + 1];
            const float k2 = kk[(dh + 1) * 3 + 2];
            a0 += k0 * v0 + k1 * v1 + k2 * v2;
            a1 += k0 * v1 + k1 * v2 + k2 * v3;
            a2 += k0 * v2 + k1 * v3 + k2 * v4;
            a3 += k0 * v3 + k1 * v4 + k2 * v5;
        }
        *(float4*)(op + h * WW + w) = make_float4(a0, a1, a2, a3);
    }
}

extern "C" void kernel_launch(void* const* d_in, const int* in_sizes, int n_in,
                              void* d_out, int out_size, void* d_ws, size_t ws_size,
                              hipStream_t stream) {
    const float* x0 = (const float*)d_in[0];  // (16,64,192,192)
    const float* d  = (const float*)d_in[1];  // (16,64)
    const float* w1 = (const float*)d_in[2];  // (64,64)
    const float* w2 = (const float*)d_in[3];  // (576,64)
    float* out = (float*)d_out;               // (16,64,192,192)
    float* ker = (float*)d_ws;                // B*C*9 = 9216 floats (36 KB)

    gen_kernels<<<BB, 256, 0, stream>>>(d, w1, w2, ker);
    dconv3x3<<<BB * CC, 256, 0, stream>>>(x0, ker, out);
}

// Round 2
// 305.262 us; speedup vs baseline: 1.0052x; 1.0052x over previous
//
#include <hip/hip_runtime.h>

// B=16, C=64, H=W=192, K=3.
// out[b,c,h,w] = sum_{i,j} ker[b,c,i,j] * x0[b,c,h+i-1,w+j-1]   (zero pad, cross-corr)
// ker[b,c,i,j] = dot(hid[b,:], w2[c*9+i*3+j, :])
// hid[b,k]     = leaky_relu(dot(d[b,:], w1[k,:]), 0.1)
//
// Fully fused: each block recomputes its plane's 9 coefficients (~5k MACs,
// w1/w2 are L1/L2 resident), then convolves a 48-row slice of the plane.
// Grid = 1024 planes x 4 slices = 4096 blocks -> 8 resident blocks/CU.

#define BB 16
#define CC 64
#define HH 192
#define WW 192
#define SPLIT 4
#define ROWS (HH / SPLIT)   // 48
#define QW (WW / 4)         // 48 float4 per row

__global__ __launch_bounds__(256) void fused_ddc(
    const float* __restrict__ x,   // (B*C, H, W)
    const float* __restrict__ d,   // (B, C)
    const float* __restrict__ w1,  // (C, C)
    const float* __restrict__ w2,  // (C*9, C)
    float* __restrict__ out)       // (B*C, H, W)
{
    __shared__ float dd[CC];
    __shared__ float hid[CC];
    __shared__ float kks[9];

    const int blk   = blockIdx.x;
    const int bc    = blk >> 2;      // plane id
    const int slice = blk & 3;
    const int b     = bc >> 6;
    const int c     = bc & 63;
    const int t     = threadIdx.x;

    if (t < CC) dd[t] = d[b * CC + t];
    __syncthreads();

    if (t < CC) {
        const float* w1r = w1 + t * CC;      // hid[t] = dot(d[b,:], w1[t,:])
        float acc = 0.f;
        #pragma unroll 8
        for (int m = 0; m < CC; ++m) acc += dd[m] * w1r[m];
        hid[t] = acc > 0.f ? acc : 0.1f * acc;
    }
    __syncthreads();

    if (t < 9) {
        const float* w2r = w2 + (c * 9 + t) * CC;   // ker coeff t
        float a0 = 0.f, a1 = 0.f;
        #pragma unroll 8
        for (int k = 0; k < CC; k += 2) {
            a0 += hid[k]     * w2r[k];
            a1 += hid[k + 1] * w2r[k + 1];
        }
        kks[t] = a0 + a1;
    }
    __syncthreads();

    float kk[9];
    #pragma unroll
    for (int i = 0; i < 9; ++i) kk[i] = kks[i];

    const float* __restrict__ xp = x   + (size_t)bc * HH * WW;
    float* __restrict__       op = out + (size_t)bc * HH * WW;
    const int h0 = slice * ROWS;

    // 48 rows x 48 quads = 2304 tasks / 256 threads = 9 iterations
    for (int idx = t; idx < ROWS * QW; idx += 256) {
        const int hl = idx / QW;
        const int qw = idx - hl * QW;
        const int h  = h0 + hl;
        const int w  = qw * 4;

        float a0 = 0.f, a1 = 0.f, a2 = 0.f, a3 = 0.f;
        #pragma unroll
        for (int dh = -1; dh <= 1; ++dh) {
            const int r = h + dh;
            if (r < 0 || r >= HH) continue;
            const float* row = xp + r * WW + w;
            const float4 cv = *(const float4*)row;
            const float v0 = (w > 0)       ? row[-1] : 0.f;
            const float v5 = (w + 4 < WW)  ? row[4]  : 0.f;
            const float k0 = kk[(dh + 1) * 3 + 0];
            const float k1 = kk[(dh + 1) * 3 + 1];
            const float k2 = kk[(dh + 1) * 3 + 2];
            a0 += k0 * v0   + k1 * cv.x + k2 * cv.y;
            a1 += k0 * cv.x + k1 * cv.y + k2 * cv.z;
            a2 += k0 * cv.y + k1 * cv.z + k2 * cv.w;
            a3 += k0 * cv.z + k1 * cv.w + k2 * v5;
        }
        *(float4*)(op + h * WW + w) = make_float4(a0, a1, a2, a3);
    }
}

extern "C" void kernel_launch(void* const* d_in, const int* in_sizes, int n_in,
                              void* d_out, int out_size, void* d_ws, size_t ws_size,
                              hipStream_t stream) {
    const float* x0 = (const float*)d_in[0];  // (16,64,192,192)
    const float* d  = (const float*)d_in[1];  // (16,64)
    const float* w1 = (const float*)d_in[2];  // (64,64)
    const float* w2 = (const float*)d_in[3];  // (576,64)
    float* out = (float*)d_out;

    fused_ddc<<<BB * CC * SPLIT, 256, 0, stream>>>(x0, d, w1, w2, out);
}

// Round 3
// 275.026 us; speedup vs baseline: 1.1157x; 1.1099x over previous
//
#include <hip/hip_runtime.h>

// B=16, C=64, H=W=192, K=3 (fixed).
// Kernel 1: ker[b,c,i,j] from the tiny MLP (16 blocks, writes 9216 floats to ws).
// Kernel 2: depthwise 3x3. Each thread owns ONE quad-column (4 cols) and 12
// consecutive output rows, with a 3-row rolling register window: per output
// row it issues exactly 1 dwordx4 + 2 scalar loads + 1 nontemporal dwordx4
// store. All 12 row loads in the unrolled loop are independent -> deep MLP.

#define BB 16
#define CC 64
#define HH 192
#define WW 192
#define KERLEN (CC * 9)     // 576 per batch
#define QW (WW / 4)         // 48 quads per row
#define RPT 12              // output rows per thread
#define TPP (QW * (HH / RPT))   // 48*16 = 768 tasks per plane
#define BPP (TPP / 256)         // 3 blocks per plane

typedef float f4 __attribute__((ext_vector_type(4)));

// ---- Kernel 1: generate the 1024 per-(b,c) 3x3 kernels into d_ws ----
__global__ __launch_bounds__(256) void gen_kernels(
    const float* __restrict__ d,   // (B, C)
    const float* __restrict__ w1,  // (C, C)
    const float* __restrict__ w2,  // (C*9, C)
    float* __restrict__ ker)       // (B*C*9)
{
    __shared__ float dd[CC];
    __shared__ float hid[CC];
    const int b = blockIdx.x;
    const int t = threadIdx.x;

    if (t < CC) dd[t] = d[b * CC + t];
    __syncthreads();

    if (t < CC) {
        const float* w1r = w1 + t * CC;
        float acc = 0.f;
        #pragma unroll 8
        for (int m = 0; m < CC; ++m) acc += dd[m] * w1r[m];
        hid[t] = acc > 0.f ? acc : 0.1f * acc;
    }
    __syncthreads();

    for (int o = t; o < KERLEN; o += 256) {
        const float* w2r = w2 + o * CC;
        float acc = 0.f;
        #pragma unroll 8
        for (int k = 0; k < CC; ++k) acc += hid[k] * w2r[k];
        ker[b * KERLEN + o] = acc;
    }
}

// ---- Kernel 2: depthwise 3x3, rolling-window column sweep ----
__global__ __launch_bounds__(256, 4) void dconv3x3_v3(
    const float* __restrict__ x,    // (B*C, H, W)
    const float* __restrict__ ker,  // (B*C, 9)
    float* __restrict__ out)        // (B*C, H, W)
{
    const int blk = blockIdx.x;
    const int bc  = blk / BPP;
    const int sub = blk - bc * BPP;

    // block-uniform coefficients -> scalar loads
    const float* kp = ker + bc * 9;
    const float k00 = kp[0], k01 = kp[1], k02 = kp[2];
    const float k10 = kp[3], k11 = kp[4], k12 = kp[5];
    const float k20 = kp[6], k21 = kp[7], k22 = kp[8];

    const int task = sub * 256 + threadIdx.x;   // 0..767
    const int rg   = task / QW;                 // row-group 0..15
    const int qw   = task - rg * QW;            // quad col 0..47
    const int w    = qw * 4;
    const int r0   = rg * RPT;

    const bool hasL = (qw > 0);
    const bool hasR = (qw < QW - 1);
    const int  offL = hasL ? -1 : 0;            // safe clamped offsets
    const int  offR = hasR ?  4 : 0;

    const float* __restrict__ xp = x   + (size_t)bc * HH * WW + w;
    float* __restrict__       op = out + (size_t)bc * HH * WW + w;

    f4 ca, cb, cc;
    float la, lb, lc, ra, rb, rc;
    const f4 zero = {0.f, 0.f, 0.f, 0.f};

    auto ld = [&](int rr, f4& c, float& l, float& r) {
        const int rcl = rr < 0 ? 0 : (rr >= HH ? HH - 1 : rr);
        const float* p = xp + rcl * WW;
        const f4 v     = *(const f4*)p;
        const float lv = p[offL];
        const float rv = p[offR];
        const bool ok  = (rr >= 0) & (rr < HH);
        c = ok ? v : zero;
        l = (ok && hasL) ? lv : 0.f;
        r = (ok && hasR) ? rv : 0.f;
    };

    ld(r0 - 1, ca, la, ra);
    ld(r0,     cb, lb, rb);

    #pragma unroll
    for (int i = 0; i < RPT; ++i) {
        ld(r0 + i + 1, cc, lc, rc);

        f4 o;
        o.x = k00 * la   + k01 * ca.x + k02 * ca.y
            + k10 * lb   + k11 * cb.x + k12 * cb.y
            + k20 * lc   + k21 * cc.x + k22 * cc.y;
        o.y = k00 * ca.x + k01 * ca.y + k02 * ca.z
            + k10 * cb.x + k11 * cb.y + k12 * cb.z
            + k20 * cc.x + k21 * cc.y + k22 * cc.z;
        o.z = k00 * ca.y + k01 * ca.z + k02 * ca.w
            + k10 * cb.y + k11 * cb.z + k12 * cb.w
            + k20 * cc.y + k21 * cc.z + k22 * cc.w;
        o.w = k00 * ca.z + k01 * ca.w + k02 * ra
            + k10 * cb.z + k11 * cb.w + k12 * rb
            + k20 * cc.z + k21 * cc.w + k22 * rc;

        __builtin_nontemporal_store(o, (f4*)(op + (size_t)(r0 + i) * WW));

        ca = cb; la = lb; ra = rb;
        cb = cc; lb = lc; rb = rc;
    }
}

extern "C" void kernel_launch(void* const* d_in, const int* in_sizes, int n_in,
                              void* d_out, int out_size, void* d_ws, size_t ws_size,
                              hipStream_t stream) {
    const float* x0 = (const float*)d_in[0];  // (16,64,192,192)
    const float* d  = (const float*)d_in[1];  // (16,64)
    const float* w1 = (const float*)d_in[2];  // (64,64)
    const float* w2 = (const float*)d_in[3];  // (576,64)
    float* out = (float*)d_out;
    float* ker = (float*)d_ws;                // 9216 floats

    gen_kernels<<<BB, 256, 0, stream>>>(d, w1, w2, ker);
    dconv3x3_v3<<<BB * CC * BPP, 256, 0, stream>>>(x0, ker, out);
}